// Round 14
// baseline (276.008 us; speedup 1.0000x reference)
//
#include <hip/hip_runtime.h>

// CG tensor-product iteration: per sample n, 34 (l1,l2,L) combos of
//   b[n,M,p,q] = sum_{i,j} x1_{l1}[n,i,p] * x2_{l2}[n,j,q] * C[i,j,M]
// packed into a (n, 39936) f32 row, keys (L,S) sorted, blocks concatenated.
//
// Model fit across R1-R13: wall ~= VALU + LDS + store-floor (SUM, not max)
// -> pipes never overlap. Cause: identical blocks launched in lockstep stay
// phase-locked (compute bursts align device-wide, then store bursts align).
// This round: 1-wave blocks (64 thr, no LDS, no barriers, 4 blocks/sample)
// + TWO rotation classes (odd blocks start the combo sequence at 17) so
// co-resident waves are half a program out of phase: one class stores
// while the other computes. Per-element math & addresses identical to R1.

namespace {

constexpr int NC = 34;

struct CInfo { int l1, l2, L, pbase, outbase, mstride; };
struct CTable { CInfo c[NC]; int packed_total; int outsize; };

constexpr CTable build_table() {
  CTable t{};
  int nb[4][2] = {};
  for (int l1 = 0; l1 < 4; ++l1)
    for (int l2 = 0; l2 < 4; ++l2) {
      int lo = l1 > l2 ? l1 - l2 : l2 - l1;
      int hi = (l1 + l2 < 3) ? l1 + l2 : 3;
      for (int L = lo; L <= hi; ++L)
        nb[L][((l1 + l2 + L) & 1) ? 0 : 1]++;
    }
  int keyoff[4][2] = {};
  int off = 0;
  for (int L = 0; L < 4; ++L)
    for (int s = 0; s < 2; ++s) {
      keyoff[L][s] = off;
      off += (2 * L + 1) * 256 * nb[L][s];
    }
  t.outsize = off;
  int blk[4][2] = {};
  int idx = 0, pb = 0;
  for (int l1 = 0; l1 < 4; ++l1)
    for (int l2 = 0; l2 < 4; ++l2) {
      int lo = l1 > l2 ? l1 - l2 : l2 - l1;
      int hi = (l1 + l2 < 3) ? l1 + l2 : 3;
      for (int L = lo; L <= hi; ++L) {
        int s = ((l1 + l2 + L) & 1) ? 0 : 1;
        pb = (pb + 15) & ~15;
        t.c[idx].l1 = l1; t.c[idx].l2 = l2; t.c[idx].L = L;
        t.c[idx].pbase = pb;
        t.c[idx].outbase = keyoff[L][s] + blk[L][s] * 256;
        t.c[idx].mstride = 256 * nb[L][s];
        blk[L][s]++;
        pb += (2 * l1 + 1) * (2 * l2 + 1) * (2 * L + 1);
        ++idx;
      }
    }
  t.packed_total = pb;
  return t;
}

constexpr CTable CTAB = build_table();
static_assert(CTAB.outsize == 39936, "output layout mismatch");
static_assert(CTAB.packed_total <= 4096, "packed cg exceeds 16KB");

// ---- coefficient pre-pack: gather cg[l1,l2,L,i,j,M] into contiguous,
// combo-major, (i,j,M)-ordered table in workspace (read order of main loop).
template <int CI>
__device__ __forceinline__ void pack_combo(const float* __restrict__ cg,
                                           float* __restrict__ cgp, int tid) {
  if constexpr (CI < NC) {
    constexpr CInfo c = CTAB.c[CI];
    constexpr int D2 = 2 * c.l2 + 1, DL = 2 * c.L + 1;
    constexpr int SZ = (2 * c.l1 + 1) * D2 * DL;
    for (int tt = tid; tt < SZ; tt += 256) {
      int M = tt % DL, ij = tt / DL;
      int j = ij % D2, i = ij / D2;
      cgp[c.pbase + tt] =
          cg[((((c.l1 * 4 + c.l2) * 4 + c.L) * 7 + i) * 7 + j) * 7 + M];
    }
    pack_combo<CI + 1>(cg, cgp, tid);
  }
}

__global__ void pack_cg_kernel(const float* __restrict__ cg,
                               float* __restrict__ cgp) {
  pack_combo<0>(cg, cgp, (int)threadIdx.x);
}

// ---- main loop: one wave per (sample, p-quartile); combo order rotated by
// ROT so co-resident waves are out of phase. Scalar acc, direct stores.
template <int ROT, int K>
__device__ __forceinline__ void run_combos(const float* __restrict__ cgp,
                                           const float (&x1r)[16],
                                           const float (&x2r)[16],
                                           float* __restrict__ outn) {
  if constexpr (K < NC) {
    constexpr CInfo c = CTAB.c[(K + ROT) % NC];
    constexpr int D1 = 2 * c.l1 + 1, D2 = 2 * c.l2 + 1, DL = 2 * c.L + 1;
    constexpr int R1 = c.l1 * c.l1, R2 = c.l2 * c.l2;  // row bases: l^2
    float acc[DL];
#pragma unroll
    for (int M = 0; M < DL; ++M) acc[M] = 0.f;
#pragma unroll
    for (int i = 0; i < D1; ++i) {
#pragma unroll
      for (int j = 0; j < D2; ++j) {
        const float ab = x1r[R1 + i] * x2r[R2 + j];
#pragma unroll
        for (int M = 0; M < DL; ++M)
          acc[M] = fmaf(cgp[c.pbase + (i * D2 + j) * DL + M], ab, acc[M]);
      }
    }
#pragma unroll
    for (int M = 0; M < DL; ++M)
      outn[c.outbase + M * c.mstride] = acc[M];
    run_combos<ROT, K + 1>(cgp, x1r, x2r, outn);
  }
}

__global__ __launch_bounds__(64) void cg_main(
    const float* __restrict__ x1_0, const float* __restrict__ x2_0,
    const float* __restrict__ x1_1, const float* __restrict__ x2_1,
    const float* __restrict__ x1_2, const float* __restrict__ x2_2,
    const float* __restrict__ x1_3, const float* __restrict__ x2_3,
    const float* __restrict__ cgp_, float* __restrict__ out) {
  const float* cgp = (const float*)__builtin_assume_aligned(cgp_, 256);
  const int lane = (int)threadIdx.x;
  const int id = (int)blockIdx.x;
  const int n = id >> 2, a = id & 3;
  const int p = a * 4 + (lane >> 4), q = lane & 15;
  // load this lane's input columns directly (16 floats each; L1/L2-hot)
  float x1r[16], x2r[16];
  {
    const float* b1[4] = {x1_0 + n * 16, x1_1 + n * 48, x1_2 + n * 80,
                          x1_3 + n * 112};
    const float* b2[4] = {x2_0 + n * 16, x2_1 + n * 48, x2_2 + n * 80,
                          x2_3 + n * 112};
#pragma unroll
    for (int l = 0; l < 4; ++l) {
#pragma unroll
      for (int i = 0; i < 2 * l + 1; ++i) {
        x1r[l * l + i] = b1[l][i * 16 + p];
        x2r[l * l + i] = b2[l][i * 16 + q];
      }
    }
  }
  float* outn = out + (size_t)n * (size_t)CTAB.outsize + a * 64 + lane;
  if (id & 1)
    run_combos<17, 0>(cgp, x1r, x2r, outn);
  else
    run_combos<0, 0>(cgp, x1r, x2r, outn);
}

}  // namespace

extern "C" void kernel_launch(void* const* d_in, const int* in_sizes, int n_in,
                              void* d_out, int out_size, void* d_ws,
                              size_t ws_size, hipStream_t stream) {
  const float* x1[4];
  const float* x2[4];
  // setup_inputs() dict order is interleaved (x1_l0, x2_l0, x1_l1, ...);
  // detect vs grouped (x1_l0..x1_l3, x2_l0..) via sizes.
  if (in_sizes[1] == in_sizes[0]) {
    for (int l = 0; l < 4; ++l) {
      x1[l] = (const float*)d_in[2 * l];
      x2[l] = (const float*)d_in[2 * l + 1];
    }
  } else {
    for (int l = 0; l < 4; ++l) {
      x1[l] = (const float*)d_in[l];
      x2[l] = (const float*)d_in[4 + l];
    }
  }
  const float* cg = (const float*)d_in[8];
  float* out = (float*)d_out;
  float* cgp = (float*)d_ws;  // packed coefficients (~16 KB)

  const int n = in_sizes[0] / 16;  // x?_l0 is (n, 1, 16)

  pack_cg_kernel<<<1, 256, 0, stream>>>(cg, cgp);
  cg_main<<<4 * n, 64, 0, stream>>>(x1[0], x2[0], x1[1], x2[1], x1[2],
                                    x2[2], x1[3], x2[3], cgp, out);
}

// Round 15
// 265.662 us; speedup vs baseline: 1.0389x; 1.0389x over previous
//
#include <hip/hip_runtime.h>

// CG tensor-product iteration: per sample n, 34 (l1,l2,L) combos of
//   b[n,M,p,q] = sum_{i,j} x1_{l1}[n,i,p] * x2_{l2}[n,j,q] * C[i,j,M]
// packed into a (n, 39936) f32 row, keys (L,S) sorted, blocks concatenated.
//
// Additive model fits all clean rounds: wall ~= VALU + LDS + HBM-write
// (pipes sum, never overlap). Hypothesis: identical blocks run in
// generation lockstep (all compute together, all store together).
// This round: R1's exact structure (one barrier, LDS input staging,
// scalar scatter stores, 256-thr blocks) + ONE change: odd blockIdx
// executes the combo sequence rotated by 17 -> co-resident blocks are a
// half-program out of phase, overlapping one class's stores with the
// other's compute. R14's attempt was confounded (1-wave blocks, scalar
// load prologue); this is the minimal-delta A/B against R1's 168.8us.

namespace {

constexpr int NC = 34;

struct CInfo { int l1, l2, L, pbase, outbase, mstride; };
struct CTable { CInfo c[NC]; int packed_total; int outsize; };

constexpr CTable build_table() {
  CTable t{};
  // count blocks per (L, S) key; s index: 0 -> S=-1, 1 -> S=+1
  int nb[4][2] = {};
  for (int l1 = 0; l1 < 4; ++l1)
    for (int l2 = 0; l2 < 4; ++l2) {
      int lo = l1 > l2 ? l1 - l2 : l2 - l1;
      int hi = (l1 + l2 < 3) ? l1 + l2 : 3;
      for (int L = lo; L <= hi; ++L)
        nb[L][((l1 + l2 + L) & 1) ? 0 : 1]++;
    }
  // per-key offsets in sorted-key order (L asc, S=-1 before S=+1)
  int keyoff[4][2] = {};
  int off = 0;
  for (int L = 0; L < 4; ++L)
    for (int s = 0; s < 2; ++s) {
      keyoff[L][s] = off;
      off += (2 * L + 1) * 256 * nb[L][s];
    }
  t.outsize = off;
  // combos in reference iteration order; packed-coeff bases 16-aligned
  int blk[4][2] = {};
  int idx = 0, pb = 0;
  for (int l1 = 0; l1 < 4; ++l1)
    for (int l2 = 0; l2 < 4; ++l2) {
      int lo = l1 > l2 ? l1 - l2 : l2 - l1;
      int hi = (l1 + l2 < 3) ? l1 + l2 : 3;
      for (int L = lo; L <= hi; ++L) {
        int s = ((l1 + l2 + L) & 1) ? 0 : 1;
        pb = (pb + 15) & ~15;
        t.c[idx].l1 = l1; t.c[idx].l2 = l2; t.c[idx].L = L;
        t.c[idx].pbase = pb;
        t.c[idx].outbase = keyoff[L][s] + blk[L][s] * 256;
        t.c[idx].mstride = 256 * nb[L][s];
        blk[L][s]++;
        pb += (2 * l1 + 1) * (2 * l2 + 1) * (2 * L + 1);
        ++idx;
      }
    }
  t.packed_total = pb;
  return t;
}

constexpr CTable CTAB = build_table();
static_assert(CTAB.outsize == 39936, "output layout mismatch");
static_assert(CTAB.packed_total <= 4096, "packed cg exceeds 16KB");

// ---- coefficient pre-pack: gather cg[l1,l2,L,i,j,M] into contiguous,
// combo-major, (i,j,M)-ordered table in workspace (read order of main loop).
template <int CI>
__device__ __forceinline__ void pack_combo(const float* __restrict__ cg,
                                           float* __restrict__ cgp, int tid) {
  if constexpr (CI < NC) {
    constexpr CInfo c = CTAB.c[CI];
    constexpr int D2 = 2 * c.l2 + 1, DL = 2 * c.L + 1;
    constexpr int SZ = (2 * c.l1 + 1) * D2 * DL;
    for (int tt = tid; tt < SZ; tt += 256) {
      int M = tt % DL, ij = tt / DL;
      int j = ij % D2, i = ij / D2;
      cgp[c.pbase + tt] =
          cg[((((c.l1 * 4 + c.l2) * 4 + c.L) * 7 + i) * 7 + j) * 7 + M];
    }
    pack_combo<CI + 1>(cg, cgp, tid);
  }
}

__global__ void pack_cg_kernel(const float* __restrict__ cg,
                               float* __restrict__ cgp) {
  pack_combo<0>(cg, cgp, (int)threadIdx.x);
}

// ---- main loop: thread = (p = tid>>4, q = tid&15); combo order rotated by
// ROT per block parity. Scalar acc, direct scatter stores (R1 structure).
template <int ROT, int K>
__device__ __forceinline__ void run_combos(const float* __restrict__ cgp,
                                           const float (&x1r)[16],
                                           const float (&x2r)[16],
                                           float* __restrict__ outn) {
  if constexpr (K < NC) {
    constexpr CInfo c = CTAB.c[(K + ROT) % NC];
    constexpr int D1 = 2 * c.l1 + 1, D2 = 2 * c.l2 + 1, DL = 2 * c.L + 1;
    constexpr int R1 = c.l1 * c.l1, R2 = c.l2 * c.l2;  // row bases: l^2
    float acc[DL];
#pragma unroll
    for (int M = 0; M < DL; ++M) acc[M] = 0.f;
#pragma unroll
    for (int i = 0; i < D1; ++i) {
#pragma unroll
      for (int j = 0; j < D2; ++j) {
        const float ab = x1r[R1 + i] * x2r[R2 + j];
#pragma unroll
        for (int M = 0; M < DL; ++M)
          acc[M] = fmaf(cgp[c.pbase + (i * D2 + j) * DL + M], ab, acc[M]);
      }
    }
#pragma unroll
    for (int M = 0; M < DL; ++M)
      outn[c.outbase + M * c.mstride] = acc[M];
    run_combos<ROT, K + 1>(cgp, x1r, x2r, outn);
  }
}

__global__ __launch_bounds__(256) void cg_main(
    const float* __restrict__ x1_0, const float* __restrict__ x2_0,
    const float* __restrict__ x1_1, const float* __restrict__ x2_1,
    const float* __restrict__ x1_2, const float* __restrict__ x2_2,
    const float* __restrict__ x1_3, const float* __restrict__ x2_3,
    const float* __restrict__ cgp_, float* __restrict__ out) {
  const float* cgp = (const float*)__builtin_assume_aligned(cgp_, 256);
  __shared__ float x1s[16][16];  // row = lm index (l^2 + i), col = Q
  __shared__ float x2s[16][16];
  const int tid = (int)threadIdx.x;
  const int n = (int)blockIdx.x;
  const int r = tid >> 4, col = tid & 15;
  // stage this sample's 2*256 input floats (each thread: 1 x1 + 1 x2 elem)
  const float* s1; const float* s2; int ri;
  if (r < 1)      { s1 = x1_0 + n * 16;  s2 = x2_0 + n * 16;  ri = r; }
  else if (r < 4) { s1 = x1_1 + n * 48;  s2 = x2_1 + n * 48;  ri = r - 1; }
  else if (r < 9) { s1 = x1_2 + n * 80;  s2 = x2_2 + n * 80;  ri = r - 4; }
  else            { s1 = x1_3 + n * 112; s2 = x2_3 + n * 112; ri = r - 9; }
  x1s[r][col] = s1[ri * 16 + col];
  x2s[r][col] = s2[ri * 16 + col];
  __syncthreads();
  // hoist this thread's columns into registers (compile-time indexed)
  float x1r[16], x2r[16];
#pragma unroll
  for (int k = 0; k < 16; ++k) {
    x1r[k] = x1s[k][r];    // p = r
    x2r[k] = x2s[k][col];  // q = col
  }
  float* outn = out + (size_t)n * (size_t)CTAB.outsize + tid;
  if (n & 1)
    run_combos<17, 0>(cgp, x1r, x2r, outn);
  else
    run_combos<0, 0>(cgp, x1r, x2r, outn);
}

}  // namespace

extern "C" void kernel_launch(void* const* d_in, const int* in_sizes, int n_in,
                              void* d_out, int out_size, void* d_ws,
                              size_t ws_size, hipStream_t stream) {
  const float* x1[4];
  const float* x2[4];
  // setup_inputs() dict order is interleaved (x1_l0, x2_l0, x1_l1, ...);
  // detect vs grouped (x1_l0..x1_l3, x2_l0..) via sizes.
  if (in_sizes[1] == in_sizes[0]) {
    for (int l = 0; l < 4; ++l) {
      x1[l] = (const float*)d_in[2 * l];
      x2[l] = (const float*)d_in[2 * l + 1];
    }
  } else {
    for (int l = 0; l < 4; ++l) {
      x1[l] = (const float*)d_in[l];
      x2[l] = (const float*)d_in[4 + l];
    }
  }
  const float* cg = (const float*)d_in[8];
  float* out = (float*)d_out;
  float* cgp = (float*)d_ws;  // packed coefficients (~16 KB)

  const int n = in_sizes[0] / 16;  // x?_l0 is (n, 1, 16)

  pack_cg_kernel<<<1, 256, 0, stream>>>(cg, cgp);
  cg_main<<<n, 256, 0, stream>>>(x1[0], x2[0], x1[1], x2[1], x1[2], x2[2],
                                 x1[3], x2[3], cgp, out);
}

// Round 16
// 148.187 us; speedup vs baseline: 1.8626x; 1.7927x over previous
//
#include <hip/hip_runtime.h>

// CG tensor-product iteration: per sample n, 34 (l1,l2,L) combos of
//   b[n,M,p,q] = sum_{i,j} x1_{l1}[n,i,p] * x2_{l2}[n,j,q] * C[i,j,M]
// packed into a (n, 39936) f32 row, keys (L,S) sorted, blocks concatenated.
//
// 15-round history: program-order write pattern irrelevant (R1 scatter ==
// R3 staged == R11 linear, 164-169us @ ~3.9 TB/s vs fill 6.6); coeff path,
// FMA count, phase desync all falsified. Last untested mechanism: the L2
// write-back path (639MB through 32MB L2 -> DRAM sees eviction order, with
// possible write-allocate/partial-line overhead). This round: R1 verbatim
// with __builtin_nontemporal_store (L2 bypass) on the barrier-free store
// path. Single lever; R5's nt test was confounded by per-pass vmcnt drains.

namespace {

constexpr int NC = 34;

struct CInfo { int l1, l2, L, pbase, outbase, mstride; };
struct CTable { CInfo c[NC]; int packed_total; int outsize; };

constexpr CTable build_table() {
  CTable t{};
  // count blocks per (L, S) key; s index: 0 -> S=-1, 1 -> S=+1
  int nb[4][2] = {};
  for (int l1 = 0; l1 < 4; ++l1)
    for (int l2 = 0; l2 < 4; ++l2) {
      int lo = l1 > l2 ? l1 - l2 : l2 - l1;
      int hi = (l1 + l2 < 3) ? l1 + l2 : 3;
      for (int L = lo; L <= hi; ++L)
        nb[L][((l1 + l2 + L) & 1) ? 0 : 1]++;
    }
  // per-key offsets in sorted-key order (L asc, S=-1 before S=+1)
  int keyoff[4][2] = {};
  int off = 0;
  for (int L = 0; L < 4; ++L)
    for (int s = 0; s < 2; ++s) {
      keyoff[L][s] = off;
      off += (2 * L + 1) * 256 * nb[L][s];
    }
  t.outsize = off;
  // combos in reference iteration order; packed-coeff bases 16-aligned
  int blk[4][2] = {};
  int idx = 0, pb = 0;
  for (int l1 = 0; l1 < 4; ++l1)
    for (int l2 = 0; l2 < 4; ++l2) {
      int lo = l1 > l2 ? l1 - l2 : l2 - l1;
      int hi = (l1 + l2 < 3) ? l1 + l2 : 3;
      for (int L = lo; L <= hi; ++L) {
        int s = ((l1 + l2 + L) & 1) ? 0 : 1;
        pb = (pb + 15) & ~15;
        t.c[idx].l1 = l1; t.c[idx].l2 = l2; t.c[idx].L = L;
        t.c[idx].pbase = pb;
        t.c[idx].outbase = keyoff[L][s] + blk[L][s] * 256;
        t.c[idx].mstride = 256 * nb[L][s];
        blk[L][s]++;
        pb += (2 * l1 + 1) * (2 * l2 + 1) * (2 * L + 1);
        ++idx;
      }
    }
  t.packed_total = pb;
  return t;
}

constexpr CTable CTAB = build_table();
static_assert(CTAB.outsize == 39936, "output layout mismatch");
static_assert(CTAB.packed_total <= 4096, "packed cg exceeds 16KB");

// ---- coefficient pre-pack: gather cg[l1,l2,L,i,j,M] into contiguous,
// combo-major, (i,j,M)-ordered table in workspace (read order of main loop).
template <int CI>
__device__ __forceinline__ void pack_combo(const float* __restrict__ cg,
                                           float* __restrict__ cgp, int tid) {
  if constexpr (CI < NC) {
    constexpr CInfo c = CTAB.c[CI];
    constexpr int D2 = 2 * c.l2 + 1, DL = 2 * c.L + 1;
    constexpr int SZ = (2 * c.l1 + 1) * D2 * DL;
    for (int tt = tid; tt < SZ; tt += 256) {
      int M = tt % DL, ij = tt / DL;
      int j = ij % D2, i = ij / D2;
      cgp[c.pbase + tt] =
          cg[((((c.l1 * 4 + c.l2) * 4 + c.L) * 7 + i) * 7 + j) * 7 + M];
    }
    pack_combo<CI + 1>(cg, cgp, tid);
  }
}

__global__ void pack_cg_kernel(const float* __restrict__ cg,
                               float* __restrict__ cgp) {
  pack_combo<0>(cg, cgp, (int)threadIdx.x);
}

// ---- main: one block per sample, thread = (p = tid>>4, q = tid&15).
// Scalar accumulation; nontemporal direct scatter stores (L2 bypass).
template <int CI>
__device__ __forceinline__ void run_combos(const float* __restrict__ cgp,
                                           const float (&x1r)[16],
                                           const float (&x2r)[16],
                                           float* __restrict__ outn) {
  if constexpr (CI < NC) {
    constexpr CInfo c = CTAB.c[CI];
    constexpr int D1 = 2 * c.l1 + 1, D2 = 2 * c.l2 + 1, DL = 2 * c.L + 1;
    constexpr int R1 = c.l1 * c.l1, R2 = c.l2 * c.l2;  // row bases: l^2
    float acc[DL];
#pragma unroll
    for (int M = 0; M < DL; ++M) acc[M] = 0.f;
#pragma unroll
    for (int i = 0; i < D1; ++i) {
#pragma unroll
      for (int j = 0; j < D2; ++j) {
        const float ab = x1r[R1 + i] * x2r[R2 + j];
#pragma unroll
        for (int M = 0; M < DL; ++M)
          acc[M] = fmaf(cgp[c.pbase + (i * D2 + j) * DL + M], ab, acc[M]);
      }
    }
#pragma unroll
    for (int M = 0; M < DL; ++M)
      __builtin_nontemporal_store(acc[M], outn + c.outbase + M * c.mstride);
    run_combos<CI + 1>(cgp, x1r, x2r, outn);
  }
}

__global__ __launch_bounds__(256) void cg_main(
    const float* __restrict__ x1_0, const float* __restrict__ x2_0,
    const float* __restrict__ x1_1, const float* __restrict__ x2_1,
    const float* __restrict__ x1_2, const float* __restrict__ x2_2,
    const float* __restrict__ x1_3, const float* __restrict__ x2_3,
    const float* __restrict__ cgp_, float* __restrict__ out) {
  const float* cgp = (const float*)__builtin_assume_aligned(cgp_, 256);
  __shared__ float x1s[16][16];  // row = lm index (l^2 + i), col = Q
  __shared__ float x2s[16][16];
  const int tid = (int)threadIdx.x;
  const int n = (int)blockIdx.x;
  const int r = tid >> 4, col = tid & 15;
  // stage this sample's 2*256 input floats (each thread: 1 x1 + 1 x2 elem)
  const float* s1; const float* s2; int ri;
  if (r < 1)      { s1 = x1_0 + n * 16;  s2 = x2_0 + n * 16;  ri = r; }
  else if (r < 4) { s1 = x1_1 + n * 48;  s2 = x2_1 + n * 48;  ri = r - 1; }
  else if (r < 9) { s1 = x1_2 + n * 80;  s2 = x2_2 + n * 80;  ri = r - 4; }
  else            { s1 = x1_3 + n * 112; s2 = x2_3 + n * 112; ri = r - 9; }
  x1s[r][col] = s1[ri * 16 + col];
  x2s[r][col] = s2[ri * 16 + col];
  __syncthreads();
  // hoist this thread's columns into registers (compile-time indexed)
  float x1r[16], x2r[16];
#pragma unroll
  for (int k = 0; k < 16; ++k) {
    x1r[k] = x1s[k][r];    // p = r
    x2r[k] = x2s[k][col];  // q = col
  }
  float* outn = out + (size_t)n * (size_t)CTAB.outsize + tid;
  run_combos<0>(cgp, x1r, x2r, outn);
}

}  // namespace

extern "C" void kernel_launch(void* const* d_in, const int* in_sizes, int n_in,
                              void* d_out, int out_size, void* d_ws,
                              size_t ws_size, hipStream_t stream) {
  const float* x1[4];
  const float* x2[4];
  // setup_inputs() dict order is interleaved (x1_l0, x2_l0, x1_l1, ...);
  // detect vs grouped (x1_l0..x1_l3, x2_l0..) via sizes.
  if (in_sizes[1] == in_sizes[0]) {
    for (int l = 0; l < 4; ++l) {
      x1[l] = (const float*)d_in[2 * l];
      x2[l] = (const float*)d_in[2 * l + 1];
    }
  } else {
    for (int l = 0; l < 4; ++l) {
      x1[l] = (const float*)d_in[l];
      x2[l] = (const float*)d_in[4 + l];
    }
  }
  const float* cg = (const float*)d_in[8];
  float* out = (float*)d_out;
  float* cgp = (float*)d_ws;  // packed coefficients (~16 KB)

  const int n = in_sizes[0] / 16;  // x?_l0 is (n, 1, 16)

  pack_cg_kernel<<<1, 256, 0, stream>>>(cg, cgp);
  cg_main<<<n, 256, 0, stream>>>(x1[0], x2[0], x1[1], x2[1], x1[2], x2[2],
                                 x1[3], x2[3], cgp, out);
}